// Round 5
// baseline (306.806 us; speedup 1.0000x reference)
//
#include <hip/hip_runtime.h>
#include <hip/hip_bf16.h>

// out[i] = probs[X[i,0]*125000 + X[i,1]*2500 + X[i,2]*50 + X[i,3]]
//
// Round-4 post-mortem: VPT=1/4/8 all land at 143-145us, FETCH ~490 MB,
// occupancy ~80% -> throughput wall (~3.65 TB/s EA traffic), not latency.
// Gather traffic 366 MB vs 184 MB per-XCD compulsory floor: ~180 MB are L2
// capacity misses caused partly by 160 MB/launch of zero-reuse stream
// allocations (X, out) thrashing the 4 MB per-XCD L2s.
// Round 5: explicit cache policy. X loads / out stores via buffer ops with
// CPol = sc0|nt|sc1 (=19: system scope + non-temporal -> no L1/L2 allocate);
// gathers stay default-cached so the table owns the L2. SRD num_records
// bounds-check handles the tail (OOB load=0, OOB store dropped) -> fully
// branch-free kernel.

typedef int v4i __attribute__((ext_vector_type(4)));

constexpr int VPT   = 8;
constexpr int BLOCK = 256;
constexpr int TILE  = BLOCK * VPT;  // 2048 samples/block

// gfx940+ CPol bits: bit0=SC0, bit1=NT, bit4=SC1
#define STREAM_POL (1 | 2 | 16)

__global__ __launch_bounds__(256) void jc_stream_kernel(
    const int* __restrict__ Xraw,
    const float* __restrict__ probs,
    float* __restrict__ out,
    int n)
{
    // SRDs: stride=0 (raw), num_records = byte size (HW bounds check),
    // word3 = 0x00020000 (raw dword access).
    auto xrs = __builtin_amdgcn_make_buffer_rsrc((void*)Xraw, (short)0,
                                                 (unsigned)n * 16u, 0x00020000);
    auto ors = __builtin_amdgcn_make_buffer_rsrc((void*)out, (short)0,
                                                 (unsigned)n * 4u, 0x00020000);

    int t = blockIdx.x * TILE + threadIdx.x;

    int idx[VPT];
    #pragma unroll
    for (int v = 0; v < VPT; ++v) {
        int i = t + v * BLOCK;
        v4i x = __builtin_amdgcn_raw_buffer_load_b128(xrs, i * 16, 0, STREAM_POL);
        idx[v] = x.x * 125000 + x.y * 2500 + x.z * 50 + x.w;
    }

    float val[VPT];
    #pragma unroll
    for (int v = 0; v < VPT; ++v)
        val[v] = probs[idx[v]];   // default policy: table keeps L1/L2

    #pragma unroll
    for (int v = 0; v < VPT; ++v) {
        int i = t + v * BLOCK;
        __builtin_amdgcn_raw_buffer_store_b32(__builtin_bit_cast(int, val[v]),
                                              ors, i * 4, 0, STREAM_POL);
    }
}

extern "C" void kernel_launch(void* const* d_in, const int* in_sizes, int n_in,
                              void* d_out, int out_size, void* d_ws, size_t ws_size,
                              hipStream_t stream) {
    const float* probs = (const float*)d_in[0];
    const int*   Xraw  = (const int*)d_in[1];   // [N,4] int32 rows
    float* out = (float*)d_out;

    int n = out_size;  // 8,000,000
    int grid = (n + TILE - 1) / TILE;  // 3907; tail handled by SRD bounds
    jc_stream_kernel<<<grid, BLOCK, 0, stream>>>(Xraw, probs, out, n);
}